// Round 11
// baseline (212.523 us; speedup 1.0000x reference)
//
#include <hip/hip_runtime.h>
#include <hip/hip_bf16.h>

#define NB   16
#define LQ   300
#define LV   8400
#define CDIM 256
#define NH   8
#define HD   32
#define NL   3
#define NP   4

typedef __bf16 bf16x8 __attribute__((ext_vector_type(8)));
typedef float  f32x4  __attribute__((ext_vector_type(4)));

// ---------------------------------------------------------------------------
// qproj: 8 queries per block. off = q@W_off+b_off ; aw = softmax per-head-12.
// ---------------------------------------------------------------------------
__global__ __launch_bounds__(256) void qproj_kernel(
    const float* __restrict__ query, const float* __restrict__ W_off,
    const float* __restrict__ b_off, const float* __restrict__ W_attn,
    const float* __restrict__ b_attn, float* __restrict__ off_out,
    float* __restrict__ aw_out)
{
    int b = blockIdx.x;             // 0..599
    int t = threadIdx.x;            // 0..255
    __shared__ float qs[8][CDIM];
    __shared__ float lg[8][96];

    #pragma unroll
    for (int g = 0; g < 8; ++g)
        qs[g][t] = query[((size_t)b * 8 + g) * CDIM + t];
    __syncthreads();

    #pragma unroll
    for (int pass = 0; pass < 2; ++pass) {
        int c = pass * 256 + t;
        if (c < 288) {
            bool isoff = c < 192;
            float acc[8] = {};
            #pragma unroll 4
            for (int k = 0; k < CDIM; ++k) {
                float w = isoff ? W_off[k * 192 + c] : W_attn[k * 96 + (c - 192)];
                #pragma unroll
                for (int g = 0; g < 8; ++g) acc[g] += qs[g][k] * w;
            }
            if (isoff) {
                float bv = b_off[c];
                #pragma unroll
                for (int g = 0; g < 8; ++g)
                    off_out[((size_t)b * 8 + g) * 192 + c] = acc[g] + bv;
            } else {
                float bv = b_attn[c - 192];
                #pragma unroll
                for (int g = 0; g < 8; ++g)
                    lg[g][c - 192] = acc[g] + bv;
            }
        }
    }
    __syncthreads();
    if (t < 64) {
        int g = t >> 3, h = t & 7;
        float m = -1e30f;
        #pragma unroll
        for (int i = 0; i < 12; ++i) m = fmaxf(m, lg[g][h * 12 + i]);
        float s = 0.f;
        #pragma unroll
        for (int i = 0; i < 12; ++i) s += expf(lg[g][h * 12 + i] - m);
        float inv = 1.f / s;
        #pragma unroll
        for (int i = 0; i < 12; ++i)
            aw_out[((size_t)b * 8 + g) * 96 + h * 12 + i] =
                expf(lg[g][h * 12 + i] - m) * inv;
    }
}

// ---------------------------------------------------------------------------
// W transpose + bf16 convert: Wt[n][k] = bf16(W[k][n]); 256x256 each.
// ---------------------------------------------------------------------------
__global__ __launch_bounds__(256) void wtrans_kernel(
    const float* __restrict__ Wv, const float* __restrict__ Wo,
    __bf16* __restrict__ Wtv, __bf16* __restrict__ Wto)
{
    const float* W = blockIdx.z ? Wo : Wv;
    __bf16* Wt = blockIdx.z ? Wto : Wtv;
    __shared__ float tile[32][33];
    int tx = threadIdx.x & 31, ty = threadIdx.x >> 5;   // 32x8
    int n0 = blockIdx.x * 32, k0 = blockIdx.y * 32;
    #pragma unroll
    for (int i = 0; i < 32; i += 8)
        tile[ty + i][tx] = W[(size_t)(k0 + ty + i) * 256 + n0 + tx];
    __syncthreads();
    #pragma unroll
    for (int i = 0; i < 32; i += 8)
        Wt[(size_t)(n0 + ty + i) * 256 + k0 + tx] = (__bf16)tile[tx][ty + i];
}

// ---------------------------------------------------------------------------
// Value-projection GEMM — LDS-FREE, BARRIER-FREE, wave-independent strips:
// C_bf16[134400,256] = A_f32 @ Bt^T + bias.
// Each wave owns 32 rows x 256 cols x K=256:
//   - A: global fp32 -> regs -> bf16 frags (a[2][8], 64 VGPR); lane l reads
//     row (l&15), k-chunk (l>>4)*8 -- the exact MFMA A-frag layout.
//   - B: frags read per-use from L2-hot 128 KB Wtv (537 MB aggregate L2,
//     overlaps the A stream). No staging.
//   - acc[2][16] = 128 VGPR; nf processed in halves to keep B-live at 32.
//   - ZERO __syncthreads, ZERO LDS: nothing can convoy; every wave is an
//     independent pipeline (the one structure class not yet tried).
// 256 thr/block (4 waves = 128 rows), grid 1050, launch_bounds(256,2).
// ---------------------------------------------------------------------------
__global__ __launch_bounds__(256, 2) void gemm_vproj(
    const float* __restrict__ A, const __bf16* __restrict__ Bt,
    const float* __restrict__ bias, __bf16* __restrict__ C)
{
    int tid  = threadIdx.x;
    int lane = tid & 63, wid = tid >> 6;
    int r16  = lane & 15, kgrp = lane >> 4;
    long row0 = (long)blockIdx.x * 128 + wid * 32;    // wave's 32-row strip

    // ---- A: 32 rows x 256 K, fp32 streamed to bf16 frags in regs ----
    bf16x8 a[2][8];
    #pragma unroll
    for (int m = 0; m < 2; ++m) {
        const float* ar = A + (row0 + m * 16 + r16) * 256 + kgrp * 8;
        float4 f[16];
        #pragma unroll
        for (int kq = 0; kq < 8; ++kq) {          // issue all 16 loads
            f[kq * 2 + 0] = *(const float4*)(ar + kq * 32 + 0);
            f[kq * 2 + 1] = *(const float4*)(ar + kq * 32 + 4);
        }
        #pragma unroll
        for (int kq = 0; kq < 8; ++kq) {
            float4 lo = f[kq * 2], hi = f[kq * 2 + 1];
            bf16x8 t;
            t[0] = (__bf16)lo.x; t[1] = (__bf16)lo.y;
            t[2] = (__bf16)lo.z; t[3] = (__bf16)lo.w;
            t[4] = (__bf16)hi.x; t[5] = (__bf16)hi.y;
            t[6] = (__bf16)hi.z; t[7] = (__bf16)hi.w;
            a[m][kq] = t;
        }
    }

    f32x4 acc[2][16];
    #pragma unroll
    for (int m = 0; m < 2; ++m)
        #pragma unroll
        for (int n = 0; n < 16; ++n)
            acc[m][n] = (f32x4){0.f, 0.f, 0.f, 0.f};

    // ---- compute: nf halves (B-live 32 VGPR), kq inner ----
    #pragma unroll
    for (int h = 0; h < 2; ++h)
        #pragma unroll
        for (int kq = 0; kq < 8; ++kq) {
            bf16x8 b[8];
            #pragma unroll
            for (int j = 0; j < 8; ++j)
                b[j] = *(const bf16x8*)&Bt[
                    (size_t)((h * 8 + j) * 16 + r16) * 256 + kq * 32 + kgrp * 8];
            #pragma unroll
            for (int m = 0; m < 2; ++m)
                #pragma unroll
                for (int j = 0; j < 8; ++j)
                    acc[m][h * 8 + j] = __builtin_amdgcn_mfma_f32_16x16x32_bf16(
                        a[m][kq], b[j], acc[m][h * 8 + j], 0, 0, 0);
        }

    // ---- epilogue: direct scattered bf16 stores (write path is strong) ----
    #pragma unroll
    for (int nf = 0; nf < 16; ++nf) {
        int col = nf * 16 + r16;
        float bv = bias[col];
        #pragma unroll
        for (int m = 0; m < 2; ++m)
            #pragma unroll
            for (int r = 0; r < 4; ++r) {
                long orow = row0 + m * 16 + kgrp * 4 + r;
                C[orow * 256 + col] = (__bf16)(acc[m][nf][r] + bv);
            }
    }
}

// ---------------------------------------------------------------------------
// Reg-staged MFMA GEMM (round-3 proven) — used for the small out-projection.
// ---------------------------------------------------------------------------
#define LDST 72
template<bool A_F32, bool C_F32>
__global__ __launch_bounds__(256) void gemm_mfma(
    const void* __restrict__ Aptr, const __bf16* __restrict__ Bt,
    const float* __restrict__ bias, void* __restrict__ Cptr, int M)
{
    __shared__ __bf16 As[128][LDST];
    __shared__ __bf16 Bs[128][LDST];
    int tid = threadIdx.x;
    int lane = tid & 63, wid = tid >> 6;
    int wr = wid >> 1, wc = wid & 1;
    int r16 = lane & 15, kgrp = lane >> 4;
    int bm = blockIdx.y, bn = blockIdx.x;

    f32x4 acc[4][4];
    #pragma unroll
    for (int m = 0; m < 4; ++m)
        #pragma unroll
        for (int n = 0; n < 4; ++n)
            acc[m][n] = (f32x4){0.f, 0.f, 0.f, 0.f};

    for (int kt = 0; kt < 256; kt += 64) {
        if (A_F32) {
            const float* A = (const float*)Aptr;
            #pragma unroll
            for (int p = 0; p < 8; ++p) {
                int row = p * 16 + (tid >> 4);
                int grow = bm * 128 + row; if (grow >= M) grow = M - 1;
                int col = (tid & 15) * 4;
                float4 a = *(const float4*)&A[(size_t)grow * 256 + kt + col];
                __bf16 pk[4] = {(__bf16)a.x, (__bf16)a.y, (__bf16)a.z, (__bf16)a.w};
                *(int2*)&As[row][col] = *(const int2*)pk;
            }
        } else {
            const __bf16* A = (const __bf16*)Aptr;
            #pragma unroll
            for (int p = 0; p < 4; ++p) {
                int row = p * 32 + (tid >> 3);
                int grow = bm * 128 + row; if (grow >= M) grow = M - 1;
                int col = (tid & 7) * 8;
                *(int4*)&As[row][col] = *(const int4*)&A[(size_t)grow * 256 + kt + col];
            }
        }
        #pragma unroll
        for (int p = 0; p < 4; ++p) {
            int row = p * 32 + (tid >> 3);
            int col = (tid & 7) * 8;
            *(int4*)&Bs[row][col] = *(const int4*)&Bt[(size_t)(bn * 128 + row) * 256 + kt + col];
        }
        __syncthreads();
        #pragma unroll
        for (int kk = 0; kk < 64; kk += 32) {
            bf16x8 af[4], bfr[4];
            #pragma unroll
            for (int m = 0; m < 4; ++m)
                af[m] = *(const bf16x8*)&As[wr * 64 + m * 16 + r16][kk + kgrp * 8];
            #pragma unroll
            for (int n = 0; n < 4; ++n)
                bfr[n] = *(const bf16x8*)&Bs[wc * 64 + n * 16 + r16][kk + kgrp * 8];
            #pragma unroll
            for (int m = 0; m < 4; ++m)
                #pragma unroll
                for (int n = 0; n < 4; ++n)
                    acc[m][n] = __builtin_amdgcn_mfma_f32_16x16x32_bf16(
                        af[m], bfr[n], acc[m][n], 0, 0, 0);
        }
        __syncthreads();
    }

    int crow0 = bm * 128 + wr * 64;
    int ccol0 = bn * 128 + wc * 64;
    #pragma unroll
    for (int n = 0; n < 4; ++n) {
        int col = ccol0 + n * 16 + r16;
        float bv = bias[col];
        #pragma unroll
        for (int m = 0; m < 4; ++m)
            #pragma unroll
            for (int r = 0; r < 4; ++r) {
                int row = crow0 + m * 16 + kgrp * 4 + r;
                if (row < M) {
                    float val = acc[m][n][r] + bv;
                    if (C_F32) ((float*)Cptr)[(size_t)row * 256 + col] = val;
                    else       ((__bf16*)Cptr)[(size_t)row * 256 + col] = (__bf16)val;
                }
            }
    }
}

// ---------------------------------------------------------------------------
// Sampler: 2 queries/block; mid written as bf16.
// ---------------------------------------------------------------------------
__global__ __launch_bounds__(256) void sample_kernel(
    const __bf16* __restrict__ v, const float* __restrict__ offb,
    const float* __restrict__ awb, const float* __restrict__ refp,
    __bf16* __restrict__ mid)
{
    int b = blockIdx.x;              // 0..2399
    int t = threadIdx.x;
    __shared__ int   offs[2][96][4];
    __shared__ float wgt [2][96][4];

    const int Hs[NL]  = {80, 40, 20};
    const int Wd[NL]  = {80, 40, 20};
    const int lvo[NL] = {0, 6400, 8000};

    if (t < 192) {
        int q2  = t >= 96;
        int idx = t - q2 * 96;       // h*12 + l*4 + p
        int nq  = b * 2 + q2;
        int lp = idx % 12, l = lp >> 2, p = lp & 3;
        int h = idx / 12;
        const float* rpq = refp + (size_t)nq * 12 + l * 4;
        float cx = rpq[0], cy = rpq[1], rw = rpq[2], rh = rpq[3];
        float ox = offb[(size_t)nq * 192 + ((h * NL + l) * NP + p) * 2 + 0];
        float oy = offb[(size_t)nq * 192 + ((h * NL + l) * NP + p) * 2 + 1];
        float a  = awb [(size_t)nq * 96 + idx];
        int W = Wd[l], H = Hs[l];
        float x = (cx + ox * 0.125f * rw) * (float)W - 0.5f;
        float y = (cy + oy * 0.125f * rh) * (float)H - 0.5f;
        float x0f = floorf(x), y0f = floorf(y);
        int x0 = (int)x0f, y0 = (int)y0f;
        float wx1 = x - x0f, wy1 = y - y0f;
        float wx0 = 1.f - wx1, wy0 = 1.f - wy1;
        float w4[4] = {wx0 * wy0, wx1 * wy0, wx0 * wy1, wx1 * wy1};
        int   xs[4] = {x0, x0 + 1, x0, x0 + 1};
        int   ys[4] = {y0, y0, y0 + 1, y0 + 1};
        #pragma unroll
        for (int cc = 0; cc < 4; ++cc) {
            bool valid = (xs[cc] >= 0) & (xs[cc] < W) & (ys[cc] >= 0) & (ys[cc] < H);
            offs[q2][idx][cc] = valid ? (lvo[l] + ys[cc] * W + xs[cc]) * 256 : 0;
            wgt [q2][idx][cc] = valid ? a * w4[cc] : 0.f;
        }
    }
    __syncthreads();

    int q2 = t >> 7, r = t & 127;
    int h = r >> 4, c2 = r & 15;
    int nq = b * 2 + q2, n = nq / LQ;
    const __bf16* vb = v + (size_t)n * LV * 256 + h * 32 + c2 * 2;
    float a0 = 0.f, a1 = 0.f;
    #pragma unroll
    for (int lp = 0; lp < 12; ++lp) {
        int idx = h * 12 + lp;
        #pragma unroll
        for (int cc = 0; cc < 4; ++cc) {
            float w = wgt[q2][idx][cc];
            int   e = offs[q2][idx][cc];
            ushort2 u = *(const ushort2*)&vb[e];
            a0 += w * __uint_as_float(((unsigned)u.x) << 16);
            a1 += w * __uint_as_float(((unsigned)u.y) << 16);
        }
    }
    __bf16 pk2[2] = {(__bf16)a0, (__bf16)a1};
    *(int*)&mid[(size_t)nq * 256 + h * 32 + c2 * 2] = *(const int*)pk2;
}

// ---------------------------------------------------------------------------
extern "C" void kernel_launch(void* const* d_in, const int* in_sizes, int n_in,
                              void* d_out, int out_size, void* d_ws, size_t ws_size,
                              hipStream_t stream)
{
    const float* query  = (const float*)d_in[0];
    const float* refp   = (const float*)d_in[1];
    const float* value  = (const float*)d_in[2];
    const float* W_off  = (const float*)d_in[3];
    const float* b_off  = (const float*)d_in[4];
    const float* W_attn = (const float*)d_in[5];
    const float* b_attn = (const float*)d_in[6];
    const float* W_val  = (const float*)d_in[7];
    const float* b_val  = (const float*)d_in[8];
    const float* W_out  = (const float*)d_in[9];
    const float* b_out  = (const float*)d_in[10];
    float* out = (float*)d_out;

    char* ws = (char*)d_ws;
    __bf16* v    = (__bf16*)ws;                          // 68,812,800 B
    float*  offb = (float*)(ws + 68812800);              //  3,686,400 B
    float*  awb  = (float*)(ws + 72499200);              //  1,843,200 B
    __bf16* mid  = (__bf16*)(ws + 74342400);             //  2,457,600 B
    __bf16* Wtv  = (__bf16*)(ws + 76800000);             //    131,072 B
    __bf16* Wto  = (__bf16*)(ws + 76931072);             //    131,072 B

    wtrans_kernel<<<dim3(8, 8, 2), 256, 0, stream>>>(W_val, W_out, Wtv, Wto);
    qproj_kernel<<<NB * LQ / 8, 256, 0, stream>>>(query, W_off, b_off, W_attn,
                                                  b_attn, offb, awb);
    // value projection: (134400 x 256) @ (256 x 256) + b_val -> bf16 v
    gemm_vproj<<<(NB * LV) / 128, 256, 0, stream>>>(value, Wtv, b_val, v);
    sample_kernel<<<NB * LQ / 2, 256, 0, stream>>>(v, offb, awb, refp, mid);
    // output projection: (4800 x 256) @ (256 x 256) + b_out -> fp32 out
    gemm_mfma<false, true><<<dim3(2, (NB * LQ + 127) / 128), 256, 0, stream>>>(
        mid, Wto, b_out, out, NB * LQ);
}

// Round 12
// 145.575 us; speedup vs baseline: 1.4599x; 1.4599x over previous
//
#include <hip/hip_runtime.h>
#include <hip/hip_bf16.h>

#define NB   16
#define LQ   300
#define LV   8400
#define CDIM 256
#define NH   8
#define HD   32
#define NL   3
#define NP   4

typedef __bf16 bf16x8 __attribute__((ext_vector_type(8)));
typedef float  f32x4  __attribute__((ext_vector_type(4)));

// ---------------------------------------------------------------------------
// W transpose + bf16 convert: Wt[n][k] = bf16(W[k][n]); 256x256 each.
// ---------------------------------------------------------------------------
__global__ __launch_bounds__(256) void wtrans_kernel(
    const float* __restrict__ Wv, const float* __restrict__ Wo,
    __bf16* __restrict__ Wtv, __bf16* __restrict__ Wto)
{
    const float* W = blockIdx.z ? Wo : Wv;
    __bf16* Wt = blockIdx.z ? Wto : Wtv;
    __shared__ float tile[32][33];
    int tx = threadIdx.x & 31, ty = threadIdx.x >> 5;   // 32x8
    int n0 = blockIdx.x * 32, k0 = blockIdx.y * 32;
    #pragma unroll
    for (int i = 0; i < 32; i += 8)
        tile[ty + i][tx] = W[(size_t)(k0 + ty + i) * 256 + n0 + tx];
    __syncthreads();
    #pragma unroll
    for (int i = 0; i < 32; i += 8)
        Wt[(size_t)(n0 + ty + i) * 256 + k0 + tx] = (__bf16)tile[tx][ty + i];
}

// ---------------------------------------------------------------------------
// Value-projection GEMM (round-10, best measured): M-axis pipelined,
// 3 tiles/block, B-in-registers. C_bf16[134400,256] = A_f32 @ Bt^T + bias.
// ---------------------------------------------------------------------------
__global__ __launch_bounds__(512, 4) void gemm_vproj(
    const float* __restrict__ A, const __bf16* __restrict__ Bt,
    const float* __restrict__ bias, __bf16* __restrict__ C)
{
    __shared__ __bf16 As[64][264];      // ~33 KB, +8 bf16 row pad
    int tid  = threadIdx.x;
    int lane = tid & 63, wid = tid >> 6;    // 8 waves
    int r16 = lane & 15, kgrp = lane >> 4;
    int bm0 = blockIdx.x * 3;               // first of 3 M-tiles

    // ---- B fragments once per block: wave wid owns cols [wid*32, +32) ----
    bf16x8 bfg[2][2][4];                    // [h2][nf][kq] = 64 VGPR
    #pragma unroll
    for (int h2 = 0; h2 < 2; ++h2)
        #pragma unroll
        for (int nf = 0; nf < 2; ++nf)
            #pragma unroll
            for (int kq = 0; kq < 4; ++kq)
                bfg[h2][nf][kq] = *(const bf16x8*)&Bt[
                    (size_t)(wid * 32 + nf * 16 + r16) * 256 +
                    h2 * 128 + kq * 32 + kgrp * 8];

    float bv0 = bias[wid * 32 + r16];
    float bv1 = bias[wid * 32 + 16 + r16];

    int row = tid >> 3, cid = tid & 7;
    const float* srcbase = A + (size_t)row * 256 + cid * 32;

    float4 fa[4];
    #pragma unroll
    for (int j = 0; j < 4; ++j)
        fa[j] = *(const float4*)(srcbase + (size_t)bm0 * 64 * 256 + j * 4);

    #pragma unroll
    for (int t = 0; t < 3; ++t) {
        int bm = bm0 + t;
        if (t) __syncthreads();
        float4 fb[4];
        #pragma unroll
        for (int j = 0; j < 4; ++j)
            fb[j] = *(const float4*)(srcbase + (size_t)bm * 64 * 256 + 16 + j * 4);
        #pragma unroll
        for (int q = 0; q < 2; ++q) {
            __bf16 pk[8];
            #pragma unroll
            for (int p = 0; p < 2; ++p) {
                float4 v4 = fa[q * 2 + p];
                pk[p * 4 + 0] = (__bf16)v4.x; pk[p * 4 + 1] = (__bf16)v4.y;
                pk[p * 4 + 2] = (__bf16)v4.z; pk[p * 4 + 3] = (__bf16)v4.w;
            }
            *(int4*)&As[row][cid * 32 + q * 8] = *(const int4*)pk;
        }
        #pragma unroll
        for (int q = 0; q < 2; ++q) {
            __bf16 pk[8];
            #pragma unroll
            for (int p = 0; p < 2; ++p) {
                float4 v4 = fb[q * 2 + p];
                pk[p * 4 + 0] = (__bf16)v4.x; pk[p * 4 + 1] = (__bf16)v4.y;
                pk[p * 4 + 2] = (__bf16)v4.z; pk[p * 4 + 3] = (__bf16)v4.w;
            }
            *(int4*)&As[row][cid * 32 + 16 + q * 8] = *(const int4*)pk;
        }
        __syncthreads();
        if (t < 2) {
            #pragma unroll
            for (int j = 0; j < 4; ++j)
                fa[j] = *(const float4*)(srcbase +
                        (size_t)(bm + 1) * 64 * 256 + j * 4);
        }
        f32x4 acc[4][2];
        #pragma unroll
        for (int m = 0; m < 4; ++m) {
            acc[m][0] = (f32x4){0.f, 0.f, 0.f, 0.f};
            acc[m][1] = (f32x4){0.f, 0.f, 0.f, 0.f};
        }
        #pragma unroll
        for (int h2 = 0; h2 < 2; ++h2)
            #pragma unroll
            for (int m = 0; m < 4; ++m)
                #pragma unroll
                for (int kq = 0; kq < 4; ++kq) {
                    bf16x8 af = *(const bf16x8*)&As[m * 16 + r16]
                                    [h2 * 128 + kq * 32 + kgrp * 8];
                    acc[m][0] = __builtin_amdgcn_mfma_f32_16x16x32_bf16(
                        af, bfg[h2][0][kq], acc[m][0], 0, 0, 0);
                    acc[m][1] = __builtin_amdgcn_mfma_f32_16x16x32_bf16(
                        af, bfg[h2][1][kq], acc[m][1], 0, 0, 0);
                }
        #pragma unroll
        for (int nf = 0; nf < 2; ++nf) {
            int col = wid * 32 + nf * 16 + r16;
            float bv = nf ? bv1 : bv0;
            #pragma unroll
            for (int m = 0; m < 4; ++m)
                #pragma unroll
                for (int r = 0; r < 4; ++r) {
                    int orow = bm * 64 + m * 16 + kgrp * 4 + r;
                    C[(size_t)orow * 256 + col] = (__bf16)(acc[m][nf][r] + bv);
                }
        }
    }
}

// ---------------------------------------------------------------------------
// FUSED qproj + softmax + sampler: 8 queries per block, off/aw never leave
// LDS (kills offb/awb global round-trips + one launch/drain boundary).
// Phase 1: q->LDS; Phase 2: off/logits; Phase 3: per-head softmax (in-place);
// Phase 4: coords/weights (768 items, 3/thread); Phase 5: 4 passes x 2
// queries of the proven ushort2 gather loop -> bf16 mid.
// ---------------------------------------------------------------------------
__global__ __launch_bounds__(256) void qsample_kernel(
    const float* __restrict__ query, const float* __restrict__ refp,
    const __bf16* __restrict__ v, const float* __restrict__ W_off,
    const float* __restrict__ b_off, const float* __restrict__ W_attn,
    const float* __restrict__ b_attn, __bf16* __restrict__ mid)
{
    int b = blockIdx.x;             // 0..599
    int t = threadIdx.x;            // 0..255
    __shared__ float qs[8][CDIM];       // 8 KB
    __shared__ float offl[8][192];      // 6 KB
    __shared__ float lg[8][96];         // 3 KB (logits -> aw in place)
    __shared__ int   offs[8][96][4];    // 12 KB
    __shared__ float wgt [8][96][4];    // 12 KB  (41 KB total)

    #pragma unroll
    for (int g = 0; g < 8; ++g)
        qs[g][t] = query[((size_t)b * 8 + g) * CDIM + t];
    __syncthreads();

    // ---- projections: 288 output cols over 2 passes ----
    #pragma unroll
    for (int pass = 0; pass < 2; ++pass) {
        int c = pass * 256 + t;
        if (c < 288) {
            bool isoff = c < 192;
            float acc[8] = {};
            #pragma unroll 4
            for (int k = 0; k < CDIM; ++k) {
                float w = isoff ? W_off[k * 192 + c] : W_attn[k * 96 + (c - 192)];
                #pragma unroll
                for (int g = 0; g < 8; ++g) acc[g] += qs[g][k] * w;
            }
            if (isoff) {
                float bv = b_off[c];
                #pragma unroll
                for (int g = 0; g < 8; ++g) offl[g][c] = acc[g] + bv;
            } else {
                float bv = b_attn[c - 192];
                #pragma unroll
                for (int g = 0; g < 8; ++g) lg[g][c - 192] = acc[g] + bv;
            }
        }
    }
    __syncthreads();

    // ---- per-head softmax, in place (thread owns (g,h)) ----
    if (t < 64) {
        int g = t >> 3, h = t & 7;
        float m = -1e30f;
        #pragma unroll
        for (int i = 0; i < 12; ++i) m = fmaxf(m, lg[g][h * 12 + i]);
        float s = 0.f;
        #pragma unroll
        for (int i = 0; i < 12; ++i) s += expf(lg[g][h * 12 + i] - m);
        float inv = 1.f / s;
        #pragma unroll
        for (int i = 0; i < 12; ++i)
            lg[g][h * 12 + i] = expf(lg[g][h * 12 + i] - m) * inv;
    }
    __syncthreads();

    // ---- coords/weights: 768 (q,idx) items, 3 per thread ----
    const int Hs[NL]  = {80, 40, 20};
    const int Wd[NL]  = {80, 40, 20};
    const int lvo[NL] = {0, 6400, 8000};
    #pragma unroll
    for (int j = 0; j < 3; ++j) {
        int item = j * 256 + t;          // 0..767
        int q  = item / 96;
        int idx = item - q * 96;         // h*12 + l*4 + p
        int lp = idx % 12, l = lp >> 2, p = lp & 3;
        int h = idx / 12;
        int nq = b * 8 + q;
        const float* rpq = refp + (size_t)nq * 12 + l * 4;
        float cx = rpq[0], cy = rpq[1], rw = rpq[2], rh = rpq[3];
        float ox = offl[q][((h * NL + l) * NP + p) * 2 + 0];
        float oy = offl[q][((h * NL + l) * NP + p) * 2 + 1];
        float a  = lg[q][idx];
        int W = Wd[l], H = Hs[l];
        float x = (cx + ox * 0.125f * rw) * (float)W - 0.5f;
        float y = (cy + oy * 0.125f * rh) * (float)H - 0.5f;
        float x0f = floorf(x), y0f = floorf(y);
        int x0 = (int)x0f, y0 = (int)y0f;
        float wx1 = x - x0f, wy1 = y - y0f;
        float wx0 = 1.f - wx1, wy0 = 1.f - wy1;
        float w4[4] = {wx0 * wy0, wx1 * wy0, wx0 * wy1, wx1 * wy1};
        int   xs[4] = {x0, x0 + 1, x0, x0 + 1};
        int   ys[4] = {y0, y0, y0 + 1, y0 + 1};
        #pragma unroll
        for (int cc = 0; cc < 4; ++cc) {
            bool valid = (xs[cc] >= 0) & (xs[cc] < W) & (ys[cc] >= 0) & (ys[cc] < H);
            offs[q][idx][cc] = valid ? (lvo[l] + ys[cc] * W + xs[cc]) * 256 : 0;
            wgt [q][idx][cc] = valid ? a * w4[cc] : 0.f;
        }
    }
    __syncthreads();

    // ---- sampling: 4 passes x 2 queries (128 lanes/query) ----
    int r = t & 127;
    int h = r >> 4, c2 = r & 15;
    #pragma unroll
    for (int pp = 0; pp < 4; ++pp) {
        int q8 = pp * 2 + (t >> 7);
        int nq = b * 8 + q8, n = nq / LQ;
        const __bf16* vb = v + (size_t)n * LV * 256 + h * 32 + c2 * 2;
        float a0 = 0.f, a1 = 0.f;
        #pragma unroll
        for (int lp = 0; lp < 12; ++lp) {
            int idx = h * 12 + lp;
            #pragma unroll
            for (int cc = 0; cc < 4; ++cc) {
                float w = wgt[q8][idx][cc];
                int   e = offs[q8][idx][cc];
                ushort2 u = *(const ushort2*)&vb[e];
                a0 += w * __uint_as_float(((unsigned)u.x) << 16);
                a1 += w * __uint_as_float(((unsigned)u.y) << 16);
            }
        }
        __bf16 pk2[2] = {(__bf16)a0, (__bf16)a1};
        *(int*)&mid[(size_t)nq * 256 + h * 32 + c2 * 2] = *(const int*)pk2;
    }
}

// ---------------------------------------------------------------------------
// Reg-staged MFMA GEMM (round-3 proven) — small out-projection.
// ---------------------------------------------------------------------------
#define LDST 72
template<bool A_F32, bool C_F32>
__global__ __launch_bounds__(256) void gemm_mfma(
    const void* __restrict__ Aptr, const __bf16* __restrict__ Bt,
    const float* __restrict__ bias, void* __restrict__ Cptr, int M)
{
    __shared__ __bf16 As[128][LDST];
    __shared__ __bf16 Bs[128][LDST];
    int tid = threadIdx.x;
    int lane = tid & 63, wid = tid >> 6;
    int wr = wid >> 1, wc = wid & 1;
    int r16 = lane & 15, kgrp = lane >> 4;
    int bm = blockIdx.y, bn = blockIdx.x;

    f32x4 acc[4][4];
    #pragma unroll
    for (int m = 0; m < 4; ++m)
        #pragma unroll
        for (int n = 0; n < 4; ++n)
            acc[m][n] = (f32x4){0.f, 0.f, 0.f, 0.f};

    for (int kt = 0; kt < 256; kt += 64) {
        if (A_F32) {
            const float* A = (const float*)Aptr;
            #pragma unroll
            for (int p = 0; p < 8; ++p) {
                int row = p * 16 + (tid >> 4);
                int grow = bm * 128 + row; if (grow >= M) grow = M - 1;
                int col = (tid & 15) * 4;
                float4 a = *(const float4*)&A[(size_t)grow * 256 + kt + col];
                __bf16 pk[4] = {(__bf16)a.x, (__bf16)a.y, (__bf16)a.z, (__bf16)a.w};
                *(int2*)&As[row][col] = *(const int2*)pk;
            }
        } else {
            const __bf16* A = (const __bf16*)Aptr;
            #pragma unroll
            for (int p = 0; p < 4; ++p) {
                int row = p * 32 + (tid >> 3);
                int grow = bm * 128 + row; if (grow >= M) grow = M - 1;
                int col = (tid & 7) * 8;
                *(int4*)&As[row][col] = *(const int4*)&A[(size_t)grow * 256 + kt + col];
            }
        }
        #pragma unroll
        for (int p = 0; p < 4; ++p) {
            int row = p * 32 + (tid >> 3);
            int col = (tid & 7) * 8;
            *(int4*)&Bs[row][col] = *(const int4*)&Bt[(size_t)(bn * 128 + row) * 256 + kt + col];
        }
        __syncthreads();
        #pragma unroll
        for (int kk = 0; kk < 64; kk += 32) {
            bf16x8 af[4], bfr[4];
            #pragma unroll
            for (int m = 0; m < 4; ++m)
                af[m] = *(const bf16x8*)&As[wr * 64 + m * 16 + r16][kk + kgrp * 8];
            #pragma unroll
            for (int n = 0; n < 4; ++n)
                bfr[n] = *(const bf16x8*)&Bs[wc * 64 + n * 16 + r16][kk + kgrp * 8];
            #pragma unroll
            for (int m = 0; m < 4; ++m)
                #pragma unroll
                for (int n = 0; n < 4; ++n)
                    acc[m][n] = __builtin_amdgcn_mfma_f32_16x16x32_bf16(
                        af[m], bfr[n], acc[m][n], 0, 0, 0);
        }
        __syncthreads();
    }

    int crow0 = bm * 128 + wr * 64;
    int ccol0 = bn * 128 + wc * 64;
    #pragma unroll
    for (int n = 0; n < 4; ++n) {
        int col = ccol0 + n * 16 + r16;
        float bv = bias[col];
        #pragma unroll
        for (int m = 0; m < 4; ++m)
            #pragma unroll
            for (int r = 0; r < 4; ++r) {
                int row = crow0 + m * 16 + kgrp * 4 + r;
                if (row < M) {
                    float val = acc[m][n][r] + bv;
                    if (C_F32) ((float*)Cptr)[(size_t)row * 256 + col] = val;
                    else       ((__bf16*)Cptr)[(size_t)row * 256 + col] = (__bf16)val;
                }
            }
    }
}

// ---------------------------------------------------------------------------
extern "C" void kernel_launch(void* const* d_in, const int* in_sizes, int n_in,
                              void* d_out, int out_size, void* d_ws, size_t ws_size,
                              hipStream_t stream)
{
    const float* query  = (const float*)d_in[0];
    const float* refp   = (const float*)d_in[1];
    const float* value  = (const float*)d_in[2];
    const float* W_off  = (const float*)d_in[3];
    const float* b_off  = (const float*)d_in[4];
    const float* W_attn = (const float*)d_in[5];
    const float* b_attn = (const float*)d_in[6];
    const float* W_val  = (const float*)d_in[7];
    const float* b_val  = (const float*)d_in[8];
    const float* W_out  = (const float*)d_in[9];
    const float* b_out  = (const float*)d_in[10];
    float* out = (float*)d_out;

    char* ws = (char*)d_ws;
    __bf16* v    = (__bf16*)ws;                          // 68,812,800 B
    __bf16* mid  = (__bf16*)(ws + 68812800);             //  2,457,600 B
    __bf16* Wtv  = (__bf16*)(ws + 71270400);             //    131,072 B
    __bf16* Wto  = (__bf16*)(ws + 71401472);             //    131,072 B

    wtrans_kernel<<<dim3(8, 8, 2), 256, 0, stream>>>(W_val, W_out, Wtv, Wto);
    // value projection: (134400 x 256) @ (256 x 256) + b_val -> bf16 v
    gemm_vproj<<<700, 512, 0, stream>>>(value, Wtv, b_val, v);
    // fused query-projection + softmax + deformable sampling -> bf16 mid
    qsample_kernel<<<NB * LQ / 8, 256, 0, stream>>>(query, refp, v, W_off,
                                                    b_off, W_attn, b_attn, mid);
    // output projection: (4800 x 256) @ (256 x 256) + b_out -> fp32 out
    gemm_mfma<false, true><<<dim3(2, (NB * LQ + 127) / 128), 256, 0, stream>>>(
        mid, Wto, b_out, out, NB * LQ);
}

// Round 13
// 142.687 us; speedup vs baseline: 1.4894x; 1.0202x over previous
//
#include <hip/hip_runtime.h>
#include <hip/hip_bf16.h>

#define NB   16
#define LQ   300
#define LV   8400
#define CDIM 256
#define NH   8
#define HD   32
#define NL   3
#define NP   4

typedef __bf16 bf16x8 __attribute__((ext_vector_type(8)));
typedef float  f32x4  __attribute__((ext_vector_type(4)));

// ---------------------------------------------------------------------------
// W_val transpose + bf16 convert: Wtv[n][k] = bf16(W_val[k][n]). 256x256.
// (W_out no longer needs transposing -- fused outproj uses it row-major fp32.)
// ---------------------------------------------------------------------------
__global__ __launch_bounds__(256) void wtrans_kernel(
    const float* __restrict__ Wv, __bf16* __restrict__ Wtv)
{
    __shared__ float tile[32][33];
    int tx = threadIdx.x & 31, ty = threadIdx.x >> 5;   // 32x8
    int n0 = blockIdx.x * 32, k0 = blockIdx.y * 32;
    #pragma unroll
    for (int i = 0; i < 32; i += 8)
        tile[ty + i][tx] = Wv[(size_t)(k0 + ty + i) * 256 + n0 + tx];
    __syncthreads();
    #pragma unroll
    for (int i = 0; i < 32; i += 8)
        Wtv[(size_t)(n0 + ty + i) * 256 + k0 + tx] = (__bf16)tile[tx][ty + i];
}

// ---------------------------------------------------------------------------
// Value-projection GEMM (round-10, best measured): M-axis pipelined,
// 3 tiles/block, B-in-registers. C_bf16[134400,256] = A_f32 @ Bt^T + bias.
// ---------------------------------------------------------------------------
__global__ __launch_bounds__(512, 4) void gemm_vproj(
    const float* __restrict__ A, const __bf16* __restrict__ Bt,
    const float* __restrict__ bias, __bf16* __restrict__ C)
{
    __shared__ __bf16 As[64][264];      // ~33 KB, +8 bf16 row pad
    int tid  = threadIdx.x;
    int lane = tid & 63, wid = tid >> 6;    // 8 waves
    int r16 = lane & 15, kgrp = lane >> 4;
    int bm0 = blockIdx.x * 3;               // first of 3 M-tiles

    bf16x8 bfg[2][2][4];                    // [h2][nf][kq] = 64 VGPR
    #pragma unroll
    for (int h2 = 0; h2 < 2; ++h2)
        #pragma unroll
        for (int nf = 0; nf < 2; ++nf)
            #pragma unroll
            for (int kq = 0; kq < 4; ++kq)
                bfg[h2][nf][kq] = *(const bf16x8*)&Bt[
                    (size_t)(wid * 32 + nf * 16 + r16) * 256 +
                    h2 * 128 + kq * 32 + kgrp * 8];

    float bv0 = bias[wid * 32 + r16];
    float bv1 = bias[wid * 32 + 16 + r16];

    int row = tid >> 3, cid = tid & 7;
    const float* srcbase = A + (size_t)row * 256 + cid * 32;

    float4 fa[4];
    #pragma unroll
    for (int j = 0; j < 4; ++j)
        fa[j] = *(const float4*)(srcbase + (size_t)bm0 * 64 * 256 + j * 4);

    #pragma unroll
    for (int t = 0; t < 3; ++t) {
        int bm = bm0 + t;
        if (t) __syncthreads();
        float4 fb[4];
        #pragma unroll
        for (int j = 0; j < 4; ++j)
            fb[j] = *(const float4*)(srcbase + (size_t)bm * 64 * 256 + 16 + j * 4);
        #pragma unroll
        for (int q = 0; q < 2; ++q) {
            __bf16 pk[8];
            #pragma unroll
            for (int p = 0; p < 2; ++p) {
                float4 v4 = fa[q * 2 + p];
                pk[p * 4 + 0] = (__bf16)v4.x; pk[p * 4 + 1] = (__bf16)v4.y;
                pk[p * 4 + 2] = (__bf16)v4.z; pk[p * 4 + 3] = (__bf16)v4.w;
            }
            *(int4*)&As[row][cid * 32 + q * 8] = *(const int4*)pk;
        }
        #pragma unroll
        for (int q = 0; q < 2; ++q) {
            __bf16 pk[8];
            #pragma unroll
            for (int p = 0; p < 2; ++p) {
                float4 v4 = fb[q * 2 + p];
                pk[p * 4 + 0] = (__bf16)v4.x; pk[p * 4 + 1] = (__bf16)v4.y;
                pk[p * 4 + 2] = (__bf16)v4.z; pk[p * 4 + 3] = (__bf16)v4.w;
            }
            *(int4*)&As[row][cid * 32 + 16 + q * 8] = *(const int4*)pk;
        }
        __syncthreads();
        if (t < 2) {
            #pragma unroll
            for (int j = 0; j < 4; ++j)
                fa[j] = *(const float4*)(srcbase +
                        (size_t)(bm + 1) * 64 * 256 + j * 4);
        }
        f32x4 acc[4][2];
        #pragma unroll
        for (int m = 0; m < 4; ++m) {
            acc[m][0] = (f32x4){0.f, 0.f, 0.f, 0.f};
            acc[m][1] = (f32x4){0.f, 0.f, 0.f, 0.f};
        }
        #pragma unroll
        for (int h2 = 0; h2 < 2; ++h2)
            #pragma unroll
            for (int m = 0; m < 4; ++m)
                #pragma unroll
                for (int kq = 0; kq < 4; ++kq) {
                    bf16x8 af = *(const bf16x8*)&As[m * 16 + r16]
                                    [h2 * 128 + kq * 32 + kgrp * 8];
                    acc[m][0] = __builtin_amdgcn_mfma_f32_16x16x32_bf16(
                        af, bfg[h2][0][kq], acc[m][0], 0, 0, 0);
                    acc[m][1] = __builtin_amdgcn_mfma_f32_16x16x32_bf16(
                        af, bfg[h2][1][kq], acc[m][1], 0, 0, 0);
                }
        #pragma unroll
        for (int nf = 0; nf < 2; ++nf) {
            int col = wid * 32 + nf * 16 + r16;
            float bv = nf ? bv1 : bv0;
            #pragma unroll
            for (int m = 0; m < 4; ++m)
                #pragma unroll
                for (int r = 0; r < 4; ++r) {
                    int orow = bm * 64 + m * 16 + kgrp * 4 + r;
                    C[(size_t)orow * 256 + col] = (__bf16)(acc[m][nf][r] + bv);
                }
        }
    }
}

// ---------------------------------------------------------------------------
// FULLY-FUSED TAIL: qproj + softmax + sampling + OUT-PROJECTION.
// 8 queries per block; mid[8][256] lives in LDS (fp32, overlaid on the dead
// qs buffer -- also removes mid's bf16 quantization), out-projection is the
// same VALU pattern as the qproj phase with row-major fp32 W_out (no
// transpose, coalesced). Replaces the 76-block (0.3/CU) gemm_mfma dispatch.
// Phases: q->LDS | off/logits | softmax | coords/weights | gather->mid(LDS)
//         | out = mid @ W_out + b_out.
// ---------------------------------------------------------------------------
__global__ __launch_bounds__(256) void qsample_kernel(
    const float* __restrict__ query, const float* __restrict__ refp,
    const __bf16* __restrict__ v, const float* __restrict__ W_off,
    const float* __restrict__ b_off, const float* __restrict__ W_attn,
    const float* __restrict__ b_attn, const float* __restrict__ W_out,
    const float* __restrict__ b_out, float* __restrict__ out)
{
    int b = blockIdx.x;             // 0..599
    int t = threadIdx.x;            // 0..255
    __shared__ float qs[8][CDIM];       // 8 KB: q in phases 1-2, mid after
    __shared__ float offl[8][192];      // 6 KB
    __shared__ float lg[8][96];         // 3 KB (logits -> aw in place)
    __shared__ int   offs[8][96][4];    // 12 KB
    __shared__ float wgt [8][96][4];    // 12 KB  (41 KB total)

    #pragma unroll
    for (int g = 0; g < 8; ++g)
        qs[g][t] = query[((size_t)b * 8 + g) * CDIM + t];
    __syncthreads();

    // ---- projections: 288 output cols over 2 passes ----
    #pragma unroll
    for (int pass = 0; pass < 2; ++pass) {
        int c = pass * 256 + t;
        if (c < 288) {
            bool isoff = c < 192;
            float acc[8] = {};
            #pragma unroll 4
            for (int k = 0; k < CDIM; ++k) {
                float w = isoff ? W_off[k * 192 + c] : W_attn[k * 96 + (c - 192)];
                #pragma unroll
                for (int g = 0; g < 8; ++g) acc[g] += qs[g][k] * w;
            }
            if (isoff) {
                float bv = b_off[c];
                #pragma unroll
                for (int g = 0; g < 8; ++g) offl[g][c] = acc[g] + bv;
            } else {
                float bv = b_attn[c - 192];
                #pragma unroll
                for (int g = 0; g < 8; ++g) lg[g][c - 192] = acc[g] + bv;
            }
        }
    }
    __syncthreads();

    // ---- per-head softmax, in place ----
    if (t < 64) {
        int g = t >> 3, h = t & 7;
        float m = -1e30f;
        #pragma unroll
        for (int i = 0; i < 12; ++i) m = fmaxf(m, lg[g][h * 12 + i]);
        float s = 0.f;
        #pragma unroll
        for (int i = 0; i < 12; ++i) s += expf(lg[g][h * 12 + i] - m);
        float inv = 1.f / s;
        #pragma unroll
        for (int i = 0; i < 12; ++i)
            lg[g][h * 12 + i] = expf(lg[g][h * 12 + i] - m) * inv;
    }
    __syncthreads();

    // ---- coords/weights: 768 (q,idx) items, 3 per thread ----
    const int Hs[NL]  = {80, 40, 20};
    const int Wd[NL]  = {80, 40, 20};
    const int lvo[NL] = {0, 6400, 8000};
    #pragma unroll
    for (int j = 0; j < 3; ++j) {
        int item = j * 256 + t;          // 0..767
        int q  = item / 96;
        int idx = item - q * 96;         // h*12 + l*4 + p
        int lp = idx % 12, l = lp >> 2, p = lp & 3;
        int h = idx / 12;
        int nq = b * 8 + q;
        const float* rpq = refp + (size_t)nq * 12 + l * 4;
        float cx = rpq[0], cy = rpq[1], rw = rpq[2], rh = rpq[3];
        float ox = offl[q][((h * NL + l) * NP + p) * 2 + 0];
        float oy = offl[q][((h * NL + l) * NP + p) * 2 + 1];
        float a  = lg[q][idx];
        int W = Wd[l], H = Hs[l];
        float x = (cx + ox * 0.125f * rw) * (float)W - 0.5f;
        float y = (cy + oy * 0.125f * rh) * (float)H - 0.5f;
        float x0f = floorf(x), y0f = floorf(y);
        int x0 = (int)x0f, y0 = (int)y0f;
        float wx1 = x - x0f, wy1 = y - y0f;
        float wx0 = 1.f - wx1, wy0 = 1.f - wy1;
        float w4[4] = {wx0 * wy0, wx1 * wy0, wx0 * wy1, wx1 * wy1};
        int   xs[4] = {x0, x0 + 1, x0, x0 + 1};
        int   ys[4] = {y0, y0, y0 + 1, y0 + 1};
        #pragma unroll
        for (int cc = 0; cc < 4; ++cc) {
            bool valid = (xs[cc] >= 0) & (xs[cc] < W) & (ys[cc] >= 0) & (ys[cc] < H);
            offs[q][idx][cc] = valid ? (lvo[l] + ys[cc] * W + xs[cc]) * 256 : 0;
            wgt [q][idx][cc] = valid ? a * w4[cc] : 0.f;
        }
    }
    __syncthreads();          // qs (query) dead from here; reused as mid

    // ---- sampling: 4 passes x 2 queries (128 lanes/query) -> mid in LDS ----
    int r = t & 127;
    int h = r >> 4, c2 = r & 15;
    #pragma unroll
    for (int pp = 0; pp < 4; ++pp) {
        int q8 = pp * 2 + (t >> 7);
        int nq = b * 8 + q8, n = nq / LQ;
        const __bf16* vb = v + (size_t)n * LV * 256 + h * 32 + c2 * 2;
        float a0 = 0.f, a1 = 0.f;
        #pragma unroll
        for (int lp = 0; lp < 12; ++lp) {
            int idx = h * 12 + lp;
            #pragma unroll
            for (int cc = 0; cc < 4; ++cc) {
                float w = wgt[q8][idx][cc];
                int   e = offs[q8][idx][cc];
                ushort2 u = *(const ushort2*)&vb[e];
                a0 += w * __uint_as_float(((unsigned)u.x) << 16);
                a1 += w * __uint_as_float(((unsigned)u.y) << 16);
            }
        }
        qs[q8][h * 32 + c2 * 2 + 0] = a0;     // fp32 mid, never leaves LDS
        qs[q8][h * 32 + c2 * 2 + 1] = a1;
    }
    __syncthreads();

    // ---- out-projection: out[8,256] = mid @ W_out + b_out (VALU, fp32) ----
    {
        int c = t;
        float acc[8] = {};
        #pragma unroll 4
        for (int k = 0; k < CDIM; ++k) {
            float w = W_out[k * 256 + c];
            #pragma unroll
            for (int g = 0; g < 8; ++g) acc[g] += qs[g][k] * w;
        }
        float bo = b_out[c];
        #pragma unroll
        for (int g = 0; g < 8; ++g)
            out[((size_t)b * 8 + g) * 256 + c] = acc[g] + bo;
    }
}

// ---------------------------------------------------------------------------
extern "C" void kernel_launch(void* const* d_in, const int* in_sizes, int n_in,
                              void* d_out, int out_size, void* d_ws, size_t ws_size,
                              hipStream_t stream)
{
    const float* query  = (const float*)d_in[0];
    const float* refp   = (const float*)d_in[1];
    const float* value  = (const float*)d_in[2];
    const float* W_off  = (const float*)d_in[3];
    const float* b_off  = (const float*)d_in[4];
    const float* W_attn = (const float*)d_in[5];
    const float* b_attn = (const float*)d_in[6];
    const float* W_val  = (const float*)d_in[7];
    const float* b_val  = (const float*)d_in[8];
    const float* W_out  = (const float*)d_in[9];
    const float* b_out  = (const float*)d_in[10];
    float* out = (float*)d_out;

    char* ws = (char*)d_ws;
    __bf16* v   = (__bf16*)ws;                           // 68,812,800 B
    __bf16* Wtv = (__bf16*)(ws + 68812800);              //    131,072 B

    wtrans_kernel<<<dim3(8, 8), 256, 0, stream>>>(W_val, Wtv);
    // value projection: (134400 x 256) @ (256 x 256) + b_val -> bf16 v
    gemm_vproj<<<700, 512, 0, stream>>>(value, Wtv, b_val, v);
    // fused qproj + softmax + sampling + out-projection -> fp32 out
    qsample_kernel<<<NB * LQ / 8, 256, 0, stream>>>(query, refp, v, W_off,
                                                    b_off, W_attn, b_attn,
                                                    W_out, b_out, out);
}